// Round 1
// baseline (1321.202 us; speedup 1.0000x reference)
//
#include <hip/hip_runtime.h>
#include <math.h>

#define B 128
#define H 32
#define D 128
#define W_SZ 128
#define TOPK 96
#define E 4096
#define BE (B * E)              // 524288
#define RING (B * H * W_SZ * D) // 67108864

#define KSPLIT 8
#define KC (E / KSPLIT)         // 512
#define NTILES (E / 128)        // 32
#define BPM (NTILES * KSPLIT)   // 256 blocks per matrix

// ---------------------------------------------------------------------------
// Bias init: Y[b,e] = bias[e] for qb/kb/vb/out. Makes the atomic split-K
// epilogue idempotent across launches/replays.
// ---------------------------------------------------------------------------
__global__ __launch_bounds__(256) void init_kernel(
    float* __restrict__ qb, float* __restrict__ kb,
    float* __restrict__ vb, float* __restrict__ out,
    const float* __restrict__ bq, const float* __restrict__ bk,
    const float* __restrict__ bv, const float* __restrict__ bo) {
    const int i = blockIdx.x * 256 + threadIdx.x;   // float4 index, 4 bufs
    const int per_buf = BE / 4;                     // 131072
    const int buf = i / per_buf;
    const int j = i - buf * per_buf;
    const int e4 = (j * 4) & (E - 1);
    const float* bias = (buf == 0) ? bq : (buf == 1) ? bk : (buf == 2) ? bv : bo;
    float* y = (buf == 0) ? qb : (buf == 1) ? kb : (buf == 2) ? vb : out;
    *(float4*)(y + (size_t)j * 4) = *(const float4*)(bias + e4);
}

// ---------------------------------------------------------------------------
// Split-K GEMM: Y[b,e] += sum_{f in k-chunk} X[b,f] * W[e,f]
// Block tile: M=128 (all batches) x N=128, K-chunk = 512 staged in BK=32
// slices. 256 threads, 8x8 register microtile -> 4 ds_read_b128 per 64 FMA
// (0.5 B/FLOP, LDS and VALU balanced). Epilogue: atomicAdd into
// bias-pre-initialized Y.
// ---------------------------------------------------------------------------
struct GemmArgs {
    const float* X;
    const float* W0; const float* W1; const float* W2;
    float* Y0; float* Y1; float* Y2;
};

__global__ __launch_bounds__(256) void gemm_kernel(GemmArgs a) {
    __shared__ __align__(16) float xs[32][132];   // xs[k][b]
    __shared__ __align__(16) float wsh[32][132];  // wsh[k][e_local]

    const int mat = blockIdx.x / BPM;
    const int rem = blockIdx.x % BPM;
    const int nt  = rem / KSPLIT;
    const int ks  = rem % KSPLIT;

    const float* Wm = (mat == 0) ? a.W0 : (mat == 1) ? a.W1 : a.W2;
    float*       Ym = (mat == 0) ? a.Y0 : (mat == 1) ? a.Y1 : a.Y2;

    const int e_base = nt * 128;
    const int k0 = ks * KC;

    const int t  = threadIdx.x;
    const int tm = (t & 15) * 4;   // batch group (0..60)
    const int tn = (t >> 4) * 4;   // col group   (0..60)

    // staging assignment: row r (0..31, +i*32), col c*4
    const int r = t >> 3;          // 0..31
    const int c = (t & 7) * 4;     // 0,4,...,28
    const float* Xg = a.X + (size_t)r * E + k0 + c;
    const float* Wg = Wm + (size_t)(e_base + r) * E + k0 + c;

    float acc[8][8];
    #pragma unroll
    for (int i = 0; i < 8; ++i)
        #pragma unroll
        for (int j = 0; j < 8; ++j) acc[i][j] = 0.0f;

    for (int kk = 0; kk < KC; kk += 32) {
        #pragma unroll
        for (int i = 0; i < 4; ++i) {
            const int rr = r + i * 32;
            float4 xv = *(const float4*)(Xg + (size_t)(i * 32) * E + kk);
            float4 wv = *(const float4*)(Wg + (size_t)(i * 32) * E + kk);
            xs[c + 0][rr] = xv.x; xs[c + 1][rr] = xv.y;
            xs[c + 2][rr] = xv.z; xs[c + 3][rr] = xv.w;
            wsh[c + 0][rr] = wv.x; wsh[c + 1][rr] = wv.y;
            wsh[c + 2][rr] = wv.z; wsh[c + 3][rr] = wv.w;
        }
        __syncthreads();

        #pragma unroll 4
        for (int k = 0; k < 32; ++k) {
            float4 x0 = *(const float4*)&xs[k][tm];
            float4 x1 = *(const float4*)&xs[k][tm + 64];
            float4 w0 = *(const float4*)&wsh[k][tn];
            float4 w1 = *(const float4*)&wsh[k][tn + 64];
            float xa[8] = {x0.x, x0.y, x0.z, x0.w, x1.x, x1.y, x1.z, x1.w};
            float wa[8] = {w0.x, w0.y, w0.z, w0.w, w1.x, w1.y, w1.z, w1.w};
            #pragma unroll
            for (int mi = 0; mi < 8; ++mi)
                #pragma unroll
                for (int nj = 0; nj < 8; ++nj)
                    acc[mi][nj] = fmaf(xa[mi], wa[nj], acc[mi][nj]);
        }
        __syncthreads();
    }

    #pragma unroll
    for (int mi = 0; mi < 8; ++mi) {
        const int m = (mi >> 2) * 64 + tm + (mi & 3);
        float* yrow = Ym + (size_t)m * E + e_base;
        #pragma unroll
        for (int nj = 0; nj < 8; ++nj) {
            const int n = (nj >> 2) * 64 + tn + (nj & 3);
            atomicAdd(yrow + n, acc[mi][nj]);
        }
    }
}

// ---------------------------------------------------------------------------
// Attention: one block per (b,h). float4/lane ring copy (2 rows per wave),
// dist^2 scores, top-96 set selection (rank + rolled-position tie-break to
// match jax.lax.top_k), softmax, weighted V. Roll skipped: (score,V-row)
// pairing is rotation-invariant.
// ---------------------------------------------------------------------------
__global__ __launch_bounds__(256) void attn_kernel(
    const float* __restrict__ qbuf, const float* __restrict__ kbuf,
    const float* __restrict__ vbuf, const float* __restrict__ log_sigma,
    const float* __restrict__ K_ring, const float* __restrict__ V_ring,
    float* __restrict__ K_new, float* __restrict__ V_new,
    float* __restrict__ cons, const int* __restrict__ cur_pos_p) {

    __shared__ __align__(16) float sq[128];
    __shared__ __align__(16) float skc[128];
    __shared__ __align__(16) float svc[128];
    __shared__ __align__(16) float sd[128];
    __shared__ __align__(16) float sp[128];
    __shared__ __align__(16) float scons[8][128];

    const int bh = blockIdx.x;
    const int b = bh >> 5, h = bh & (H - 1);
    const int t = threadIdx.x;
    const int wave = t >> 6, lane = t & 63;
    const int grp = lane >> 5;        // 0/1: which row of the pair
    const int l2 = lane & 31;
    const size_t base = (size_t)bh * (W_SZ * D);
    const size_t qoff = (size_t)b * E + h * D;

    const int cur_pos = *cur_pos_p;
    const int idx = cur_pos & (W_SZ - 1);
    const int start = (cur_pos + 1) & (W_SZ - 1);
    const int row0 = wave * 2 + grp;  // 0..7

    if (t < 128) {
        sq[t]  = qbuf[qoff + t];
        skc[t] = kbuf[qoff + t];
        svc[t] = vbuf[qoff + t];
    }
    __syncthreads();

    // ---- K pass: copy + dist^2 (8 rows per sweep, 16 sweeps) ----
    for (int w = row0; w < W_SZ; w += 8) {
        float4 kv;
        if (w == idx) kv = *(const float4*)&skc[l2 * 4];
        else          kv = *(const float4*)(K_ring + base + (size_t)w * D + l2 * 4);
        *(float4*)(K_new + base + (size_t)w * D + l2 * 4) = kv;
        float4 qv = *(const float4*)&sq[l2 * 4];
        float d0 = qv.x - kv.x, d1 = qv.y - kv.y;
        float d2 = qv.z - kv.z, d3 = qv.w - kv.w;
        float ss = d0 * d0 + d1 * d1 + d2 * d2 + d3 * d3;
        #pragma unroll
        for (int off = 16; off; off >>= 1) ss += __shfl_down(ss, off, 32);
        if (l2 == 0) sd[w] = ss;
    }
    __syncthreads();

    // ---- scores ----
    const float inv2s = 0.5f * expf(-2.0f * log_sigma[h]);  // 1/(2*sigma^2)
    if (t < 128) sd[t] = -sd[t] * inv2s;
    __syncthreads();

    // ---- top-96 set + exp ----
    float my_e = 0.0f;
    if (t < 128) {
        const float my_s = sd[t];
        const int my_p = (t - start) & (W_SZ - 1);  // rolled position
        int rank = 0;
        float mx = -1e30f;
        for (int w2 = 0; w2 < W_SZ; ++w2) {
            float s2 = sd[w2];
            mx = fmaxf(mx, s2);
            int p2 = (w2 - start) & (W_SZ - 1);
            rank += (s2 > my_s) || (s2 == my_s && p2 < my_p);
        }
        if (rank < TOPK) my_e = expf(my_s - mx);
    }
    __syncthreads();
    if (t < 128) sp[t] = my_e;
    __syncthreads();

    float denom = 0.0f;
    for (int w2 = 0; w2 < W_SZ; ++w2) denom += sp[w2];
    const float invd = 1.0f / denom;

    // ---- V pass: copy + weighted sum ----
    float4 av = {0.0f, 0.0f, 0.0f, 0.0f};
    for (int w = row0; w < W_SZ; w += 8) {
        float4 vv;
        if (w == idx) vv = *(const float4*)&svc[l2 * 4];
        else          vv = *(const float4*)(V_ring + base + (size_t)w * D + l2 * 4);
        *(float4*)(V_new + base + (size_t)w * D + l2 * 4) = vv;
        float pw = sp[w] * invd;
        av.x = fmaf(pw, vv.x, av.x);
        av.y = fmaf(pw, vv.y, av.y);
        av.z = fmaf(pw, vv.z, av.z);
        av.w = fmaf(pw, vv.w, av.w);
    }
    *(float4*)&scons[row0][l2 * 4] = av;
    __syncthreads();
    if (t < 128) {
        float s = 0.0f;
        #pragma unroll
        for (int i = 0; i < 8; ++i) s += scons[i][t];
        cons[qoff + t] = s;
    }
}

// ---------------------------------------------------------------------------
extern "C" void kernel_launch(void* const* d_in, const int* in_sizes, int n_in,
                              void* d_out, int out_size, void* d_ws, size_t ws_size,
                              hipStream_t stream) {
    (void)in_sizes; (void)n_in; (void)out_size; (void)ws_size;

    const float* x   = (const float*)d_in[0];
    const float* Wq  = (const float*)d_in[1];
    const float* bq  = (const float*)d_in[2];
    const float* Wk  = (const float*)d_in[3];
    const float* bk  = (const float*)d_in[4];
    const float* Wv  = (const float*)d_in[5];
    const float* bv  = (const float*)d_in[6];
    const float* Wo  = (const float*)d_in[7];
    const float* bo  = (const float*)d_in[8];
    const float* ls  = (const float*)d_in[9];
    const float* K_ring = (const float*)d_in[10];
    const float* V_ring = (const float*)d_in[11];
    const int*   cur_pos = (const int*)d_in[12];

    float* out   = (float*)d_out;
    float* K_new = out + BE;
    float* V_new = K_new + (size_t)RING;

    float* ws = (float*)d_ws;
    float* qb = ws;
    float* kb = ws + (size_t)BE;
    float* vb = ws + 2 * (size_t)BE;
    float* cb = ws + 3 * (size_t)BE;

    // Bias-init q/k/v/out (atomic split-K epilogue accumulates on top)
    hipLaunchKernelGGL(init_kernel, dim3(BE / 256), dim3(256), 0, stream,
                       qb, kb, vb, out, bq, bk, bv, bo);

    // QKV projections: 3 mats x 32 n-tiles x 8 k-splits = 768 blocks (3/CU)
    GemmArgs ga;
    ga.X = x;
    ga.W0 = Wq; ga.W1 = Wk; ga.W2 = Wv;
    ga.Y0 = qb; ga.Y1 = kb; ga.Y2 = vb;
    hipLaunchKernelGGL(gemm_kernel, dim3(3 * BPM), dim3(256), 0, stream, ga);

    // Attention + ring copy (one block per (b,h))
    hipLaunchKernelGGL(attn_kernel, dim3(B * H), dim3(256), 0, stream,
                       qb, kb, vb, ls, K_ring, V_ring, K_new, V_new, cb, cur_pos);

    // Output projection: 32 n-tiles x 8 k-splits = 256 blocks
    GemmArgs go;
    go.X = cb;
    go.W0 = Wo; go.W1 = Wo; go.W2 = Wo;
    go.Y0 = out; go.Y1 = out; go.Y2 = out;
    hipLaunchKernelGGL(gemm_kernel, dim3(BPM), dim3(256), 0, stream, go);
}